// Round 1
// baseline (138.688 us; speedup 1.0000x reference)
//
#include <hip/hip_runtime.h>
#include <math.h>

#define B_DIM   1024
#define IN_DIMS 512
#define OUT_DIMS 512
#define MOD_DIM 256
#define EPS_F   1e-8f

// -------------------------------------------------------------------------
// Kernel 1: colsum[i] = sum_o weight[o][i]^2   (weight is [OUT, IN] row-major)
// grid = IN/64 blocks x 256 threads. Lanes sweep 64 consecutive columns
// (coalesced 256B per wave), 4 o-rows in parallel per block.
// -------------------------------------------------------------------------
__global__ __launch_bounds__(256) void colsum_kernel(
    const float* __restrict__ weight, float* __restrict__ colsum)
{
    __shared__ float sm[4][64];
    const int c  = threadIdx.x & 63;
    const int r0 = threadIdx.x >> 6;
    const int col = blockIdx.x * 64 + c;
    float acc = 0.f;
    for (int o = r0; o < OUT_DIMS; o += 4) {
        float w = weight[o * IN_DIMS + col];
        acc += w * w;
    }
    sm[r0][c] = acc;
    __syncthreads();
    if (r0 == 0) {
        colsum[col] = sm[0][c] + sm[1][c] + sm[2][c] + sm[3][c];
    }
}

// -------------------------------------------------------------------------
// NT GEMM: C[m,n] = sum_k A[m,k] * Bm[n,k]  (+ epilogue)
// A: [M,K] row-major, Bm: [N,K] row-major, K = lda = ldb. LDC = 512.
// Tile 64x64, BK=32, 256 threads (16x16), 4x4 micro-tile/thread.
// LDS stored K-major transposed ([k][row], stride 68) so the inner loop
// reads one ds_read_b128 per operand per k.
// EPI_T: t-epilogue  s = acc + vec[col]; C = x * s * rsqrt(s*s*colsum + eps)
// else : out-epilogue C = acc + vec[col]
// -------------------------------------------------------------------------
template <int K, bool EPI_T>
__global__ __launch_bounds__(256) void gemm_nt(
    const float* __restrict__ A,
    const float* __restrict__ Bm,
    const float* __restrict__ vec,      // mod_b (EPI_T) or bias
    const float* __restrict__ xin,      // x (EPI_T only)
    const float* __restrict__ colsum,   // (EPI_T only)
    float* __restrict__ C)
{
    constexpr int BK = 32;
    constexpr int LS = 68;              // LDS row stride (floats), 16B-aligned
    __shared__ float As[BK][LS];
    __shared__ float Bs[BK][LS];

    const int tid = threadIdx.x;
    const int tx = tid & 15;            // -> 4 cols (n)
    const int ty = tid >> 4;            // -> 4 rows (m)
    const int bm = blockIdx.y;          // m-tile
    const int bn = blockIdx.x;          // n-tile

    float acc[4][4] = {};

    for (int kt = 0; kt < K; kt += BK) {
        // ---- stage A,B tiles: 64 rows x 32 k, 2 float4 per thread each ----
        #pragma unroll
        for (int i = 0; i < 2; i++) {
            const int q  = tid + i * 256;
            const int r  = q >> 3;          // 0..63
            const int k4 = (q & 7) << 2;    // 0..28
            float4 va = *(const float4*)&A [(bm * 64 + r) * K + kt + k4];
            As[k4 + 0][r] = va.x; As[k4 + 1][r] = va.y;
            As[k4 + 2][r] = va.z; As[k4 + 3][r] = va.w;
            float4 vb = *(const float4*)&Bm[(bn * 64 + r) * K + kt + k4];
            Bs[k4 + 0][r] = vb.x; Bs[k4 + 1][r] = vb.y;
            Bs[k4 + 2][r] = vb.z; Bs[k4 + 3][r] = vb.w;
        }
        __syncthreads();

        // ---- inner product: 32 k-steps, 2x ds_read_b128 + 16 FMA each ----
        #pragma unroll
        for (int k = 0; k < BK; k++) {
            float4 a = *(const float4*)&As[k][ty * 4];
            float4 b = *(const float4*)&Bs[k][tx * 4];
            acc[0][0] += a.x * b.x; acc[0][1] += a.x * b.y;
            acc[0][2] += a.x * b.z; acc[0][3] += a.x * b.w;
            acc[1][0] += a.y * b.x; acc[1][1] += a.y * b.y;
            acc[1][2] += a.y * b.z; acc[1][3] += a.y * b.w;
            acc[2][0] += a.z * b.x; acc[2][1] += a.z * b.y;
            acc[2][2] += a.z * b.z; acc[2][3] += a.z * b.w;
            acc[3][0] += a.w * b.x; acc[3][1] += a.w * b.y;
            acc[3][2] += a.w * b.z; acc[3][3] += a.w * b.w;
        }
        __syncthreads();
    }

    // ---- epilogue: float4 per output row-quad (coalesced 256B/wave) ----
    const int row0 = bm * 64 + ty * 4;
    const int col0 = bn * 64 + tx * 4;
    float4 vv = *(const float4*)&vec[col0];
    if (EPI_T) {
        float4 cs = *(const float4*)&colsum[col0];
        #pragma unroll
        for (int rr = 0; rr < 4; rr++) {
            const int row = row0 + rr;
            float4 xv = *(const float4*)&xin[row * 512 + col0];
            float s0 = acc[rr][0] + vv.x;
            float s1 = acc[rr][1] + vv.y;
            float s2 = acc[rr][2] + vv.z;
            float s3 = acc[rr][3] + vv.w;
            float4 o;
            o.x = xv.x * s0 * rsqrtf(s0 * s0 * cs.x + EPS_F);
            o.y = xv.y * s1 * rsqrtf(s1 * s1 * cs.y + EPS_F);
            o.z = xv.z * s2 * rsqrtf(s2 * s2 * cs.z + EPS_F);
            o.w = xv.w * s3 * rsqrtf(s3 * s3 * cs.w + EPS_F);
            *(float4*)&C[row * 512 + col0] = o;
        }
    } else {
        #pragma unroll
        for (int rr = 0; rr < 4; rr++) {
            const int row = row0 + rr;
            float4 o;
            o.x = acc[rr][0] + vv.x;
            o.y = acc[rr][1] + vv.y;
            o.z = acc[rr][2] + vv.z;
            o.w = acc[rr][3] + vv.w;
            *(float4*)&C[row * 512 + col0] = o;
        }
    }
}

extern "C" void kernel_launch(void* const* d_in, const int* in_sizes, int n_in,
                              void* d_out, int out_size, void* d_ws, size_t ws_size,
                              hipStream_t stream)
{
    const float* modulations = (const float*)d_in[0]; // [1024, 256]
    const float* x           = (const float*)d_in[1]; // [1024, 512]
    const float* weight      = (const float*)d_in[2]; // [512, 512]
    const float* bias        = (const float*)d_in[3]; // [512]
    const float* mod_w       = (const float*)d_in[4]; // [512, 256]
    const float* mod_b       = (const float*)d_in[5]; // [512]
    float* out = (float*)d_out;                       // [1024, 512]

    float* ws      = (float*)d_ws;
    float* colsum  = ws;              // 512 floats
    float* t_buf   = ws + 1024;       // 1024*512 floats, 4KB-offset (16B aligned)

    // 1) colsum[i] = sum_o weight[o,i]^2
    colsum_kernel<<<IN_DIMS / 64, 256, 0, stream>>>(weight, colsum);

    // 2) t[b,i] = x[b,i] * s * rsqrt(s^2*colsum[i]+eps),
    //    s = modulations[b,:] . mod_w[i,:] + mod_b[i]
    gemm_nt<MOD_DIM, true><<<dim3(IN_DIMS / 64, B_DIM / 64), 256, 0, stream>>>(
        modulations, mod_w, mod_b, x, colsum, t_buf);

    // 3) out[b,o] = t[b,:] . weight[o,:] + bias[o]
    gemm_nt<IN_DIMS, false><<<dim3(OUT_DIMS / 64, B_DIM / 64), 256, 0, stream>>>(
        t_buf, weight, bias, nullptr, nullptr, out);
}

// Round 2
// 91.579 us; speedup vs baseline: 1.5144x; 1.5144x over previous
//
#include <hip/hip_runtime.h>
#include <math.h>

#define B_DIM    1024
#define IN_DIMS  512
#define OUT_DIMS 512
#define MOD_DIM  256
#define EPS_F    1e-8f
#define SP       72        // LDS row stride in bf16 elements (144B: 16B-aligned, ~2-way banks)

typedef __attribute__((ext_vector_type(8))) short bf16x8;
typedef __attribute__((ext_vector_type(4))) float f32x4;

__device__ __forceinline__ unsigned short f2bf(float f) {
    union { float f; unsigned u; } c; c.f = f;
    unsigned r = c.u + 0x7fffu + ((c.u >> 16) & 1u);   // RNE
    return (unsigned short)(r >> 16);
}
__device__ __forceinline__ float bf2f(unsigned short h) {
    union { float f; unsigned u; } c; c.u = ((unsigned)h) << 16;
    return c.f;
}

// ---------------------------------------------------------------------------
// prep_w: colsum[i] = sum_o weight[o][i]^2  AND  w_bf = bf16(weight)
// 8 blocks x 256 thr. thread: q=col-quad (16 per block=64 cols), r=row lane
// (16), 32 fully-unrolled float4 loads -> deep MLP instead of round-1's
// serialized chain.
// ---------------------------------------------------------------------------
__global__ __launch_bounds__(256) void prep_w(
    const float* __restrict__ weight, float* __restrict__ colsum,
    unsigned short* __restrict__ w_bf)
{
    __shared__ float4 sm[16][16];
    const int q = threadIdx.x & 15;
    const int r = threadIdx.x >> 4;
    const int col = blockIdx.x * 64 + q * 4;
    float4 acc = {0.f, 0.f, 0.f, 0.f};
    #pragma unroll
    for (int it = 0; it < 32; it++) {
        const int row = r + 16 * it;
        float4 v = *(const float4*)&weight[row * IN_DIMS + col];
        acc.x += v.x * v.x; acc.y += v.y * v.y;
        acc.z += v.z * v.z; acc.w += v.w * v.w;
        ushort4 h;
        h.x = f2bf(v.x); h.y = f2bf(v.y); h.z = f2bf(v.z); h.w = f2bf(v.w);
        *(ushort4*)&w_bf[row * IN_DIMS + col] = h;
    }
    sm[r][q] = acc;
    __syncthreads();
    if (threadIdx.x < 16) {
        float4 s = sm[0][threadIdx.x];
        #pragma unroll
        for (int j = 1; j < 16; j++) {
            float4 v = sm[j][threadIdx.x];
            s.x += v.x; s.y += v.y; s.z += v.z; s.w += v.w;
        }
        *(float4*)&colsum[blockIdx.x * 64 + threadIdx.x * 4] = s;
    }
}

// ---------------------------------------------------------------------------
// gemm_mod: scales = modulations @ mod_w^T + mod_b  in split-bf16 (hi/lo),
// epilogue t = x * s * rsqrt(s^2*colsum + eps) -> t_bf (bf16).
// Tile 64x64, BK=64, 256 thr = 4 waves of 32x32 (2x2 of 16x16x32 MFMA).
// Split: s = hi*hi + hi*lo + lo*hi  (error ~2^-18 rel; protects the
// sign(s)-like epilogue near s=0).
// ---------------------------------------------------------------------------
__global__ __launch_bounds__(256) void gemm_mod(
    const float* __restrict__ A,      // modulations [1024,256]
    const float* __restrict__ Bw,     // mod_w [512,256]
    const float* __restrict__ mod_b,  // [512]
    const float* __restrict__ x,      // [1024,512]
    const float* __restrict__ colsum, // [512]
    unsigned short* __restrict__ t_bf)// [1024,512]
{
    __shared__ unsigned short Ah[64 * SP], Al[64 * SP], Bh[64 * SP], Bl[64 * SP];
    const int tid = threadIdx.x;
    const int m0 = blockIdx.y * 64, n0 = blockIdx.x * 64;
    const int lane = tid & 63, wv = tid >> 6;
    const int wm = (wv >> 1) * 32, wn = (wv & 1) * 32;
    const int lr = lane & 15, lq = lane >> 4;

    f32x4 acc[2][2] = {};

    for (int kt = 0; kt < MOD_DIM; kt += 64) {
        #pragma unroll
        for (int i = 0; i < 4; i++) {
            const int idx = tid + i * 256;      // 0..1023
            const int r  = idx >> 4;            // 64 rows
            const int k4 = (idx & 15) * 4;      // 64 k / float4
            float4 va = *(const float4*)&A[(m0 + r) * MOD_DIM + kt + k4];
            ushort4 h, l;
            h.x = f2bf(va.x); l.x = f2bf(va.x - bf2f(h.x));
            h.y = f2bf(va.y); l.y = f2bf(va.y - bf2f(h.y));
            h.z = f2bf(va.z); l.z = f2bf(va.z - bf2f(h.z));
            h.w = f2bf(va.w); l.w = f2bf(va.w - bf2f(h.w));
            *(ushort4*)&Ah[r * SP + k4] = h;
            *(ushort4*)&Al[r * SP + k4] = l;
            float4 vb = *(const float4*)&Bw[(n0 + r) * MOD_DIM + kt + k4];
            h.x = f2bf(vb.x); l.x = f2bf(vb.x - bf2f(h.x));
            h.y = f2bf(vb.y); l.y = f2bf(vb.y - bf2f(h.y));
            h.z = f2bf(vb.z); l.z = f2bf(vb.z - bf2f(h.z));
            h.w = f2bf(vb.w); l.w = f2bf(vb.w - bf2f(h.w));
            *(ushort4*)&Bh[r * SP + k4] = h;
            *(ushort4*)&Bl[r * SP + k4] = l;
        }
        __syncthreads();

        #pragma unroll
        for (int kk = 0; kk < 64; kk += 32) {
            const int ko = kk + lq * 8;
            bf16x8 ah0 = *(bf16x8*)&Ah[(wm +      lr) * SP + ko];
            bf16x8 ah1 = *(bf16x8*)&Ah[(wm + 16 + lr) * SP + ko];
            bf16x8 al0 = *(bf16x8*)&Al[(wm +      lr) * SP + ko];
            bf16x8 al1 = *(bf16x8*)&Al[(wm + 16 + lr) * SP + ko];
            bf16x8 bh0 = *(bf16x8*)&Bh[(wn +      lr) * SP + ko];
            bf16x8 bh1 = *(bf16x8*)&Bh[(wn + 16 + lr) * SP + ko];
            bf16x8 bl0 = *(bf16x8*)&Bl[(wn +      lr) * SP + ko];
            bf16x8 bl1 = *(bf16x8*)&Bl[(wn + 16 + lr) * SP + ko];
            acc[0][0] = __builtin_amdgcn_mfma_f32_16x16x32_bf16(ah0, bh0, acc[0][0], 0, 0, 0);
            acc[0][1] = __builtin_amdgcn_mfma_f32_16x16x32_bf16(ah0, bh1, acc[0][1], 0, 0, 0);
            acc[1][0] = __builtin_amdgcn_mfma_f32_16x16x32_bf16(ah1, bh0, acc[1][0], 0, 0, 0);
            acc[1][1] = __builtin_amdgcn_mfma_f32_16x16x32_bf16(ah1, bh1, acc[1][1], 0, 0, 0);
            acc[0][0] = __builtin_amdgcn_mfma_f32_16x16x32_bf16(ah0, bl0, acc[0][0], 0, 0, 0);
            acc[0][1] = __builtin_amdgcn_mfma_f32_16x16x32_bf16(ah0, bl1, acc[0][1], 0, 0, 0);
            acc[1][0] = __builtin_amdgcn_mfma_f32_16x16x32_bf16(ah1, bl0, acc[1][0], 0, 0, 0);
            acc[1][1] = __builtin_amdgcn_mfma_f32_16x16x32_bf16(ah1, bl1, acc[1][1], 0, 0, 0);
            acc[0][0] = __builtin_amdgcn_mfma_f32_16x16x32_bf16(al0, bh0, acc[0][0], 0, 0, 0);
            acc[0][1] = __builtin_amdgcn_mfma_f32_16x16x32_bf16(al0, bh1, acc[0][1], 0, 0, 0);
            acc[1][0] = __builtin_amdgcn_mfma_f32_16x16x32_bf16(al1, bh0, acc[1][0], 0, 0, 0);
            acc[1][1] = __builtin_amdgcn_mfma_f32_16x16x32_bf16(al1, bh1, acc[1][1], 0, 0, 0);
        }
        __syncthreads();
    }

    // epilogue: s -> t (bf16). C/D layout: col = lane&15, row = (lane>>4)*4+reg
    #pragma unroll
    for (int i = 0; i < 2; i++) {
        #pragma unroll
        for (int j = 0; j < 2; j++) {
            const int gn = n0 + wn + 16 * j + lr;
            const float cs = colsum[gn];
            const float mb = mod_b[gn];
            #pragma unroll
            for (int rr = 0; rr < 4; rr++) {
                const int gm = m0 + wm + 16 * i + lq * 4 + rr;
                const float s = acc[i][j][rr] + mb;
                const float tv = x[gm * IN_DIMS + gn] * s * rsqrtf(s * s * cs + EPS_F);
                t_bf[gm * IN_DIMS + gn] = f2bf(tv);
            }
        }
    }
}

// ---------------------------------------------------------------------------
// gemm_out: out = t_bf @ w_bf^T + bias  (plain bf16 MFMA, fp32 accumulate)
// Same 64x64 tile / 4-wave 32x32 structure; K=512.
// ---------------------------------------------------------------------------
__global__ __launch_bounds__(256) void gemm_out(
    const unsigned short* __restrict__ A,  // t_bf [1024,512]
    const unsigned short* __restrict__ Bw, // w_bf [512,512]
    const float* __restrict__ bias,        // [512]
    float* __restrict__ out)               // [1024,512]
{
    __shared__ unsigned short As[64 * SP], Bs[64 * SP];
    const int tid = threadIdx.x;
    const int m0 = blockIdx.y * 64, n0 = blockIdx.x * 64;
    const int lane = tid & 63, wv = tid >> 6;
    const int wm = (wv >> 1) * 32, wn = (wv & 1) * 32;
    const int lr = lane & 15, lq = lane >> 4;

    f32x4 acc[2][2] = {};

    for (int kt = 0; kt < IN_DIMS; kt += 64) {
        #pragma unroll
        for (int i = 0; i < 2; i++) {
            const int idx = tid + i * 256;      // 0..511
            const int r  = idx >> 3;            // 64 rows
            const int k8 = (idx & 7) * 8;       // 64 k / 8-elem chunk (16B)
            *(uint4*)&As[r * SP + k8] = *(const uint4*)&A [(m0 + r) * IN_DIMS + kt + k8];
            *(uint4*)&Bs[r * SP + k8] = *(const uint4*)&Bw[(n0 + r) * IN_DIMS + kt + k8];
        }
        __syncthreads();

        #pragma unroll
        for (int kk = 0; kk < 64; kk += 32) {
            const int ko = kk + lq * 8;
            bf16x8 a0 = *(bf16x8*)&As[(wm +      lr) * SP + ko];
            bf16x8 a1 = *(bf16x8*)&As[(wm + 16 + lr) * SP + ko];
            bf16x8 b0 = *(bf16x8*)&Bs[(wn +      lr) * SP + ko];
            bf16x8 b1 = *(bf16x8*)&Bs[(wn + 16 + lr) * SP + ko];
            acc[0][0] = __builtin_amdgcn_mfma_f32_16x16x32_bf16(a0, b0, acc[0][0], 0, 0, 0);
            acc[0][1] = __builtin_amdgcn_mfma_f32_16x16x32_bf16(a0, b1, acc[0][1], 0, 0, 0);
            acc[1][0] = __builtin_amdgcn_mfma_f32_16x16x32_bf16(a1, b0, acc[1][0], 0, 0, 0);
            acc[1][1] = __builtin_amdgcn_mfma_f32_16x16x32_bf16(a1, b1, acc[1][1], 0, 0, 0);
        }
        __syncthreads();
    }

    #pragma unroll
    for (int i = 0; i < 2; i++) {
        #pragma unroll
        for (int j = 0; j < 2; j++) {
            const int gn = n0 + wn + 16 * j + lr;
            const float bv = bias[gn];
            #pragma unroll
            for (int rr = 0; rr < 4; rr++) {
                const int gm = m0 + wm + 16 * i + lq * 4 + rr;
                out[gm * OUT_DIMS + gn] = acc[i][j][rr] + bv;
            }
        }
    }
}

extern "C" void kernel_launch(void* const* d_in, const int* in_sizes, int n_in,
                              void* d_out, int out_size, void* d_ws, size_t ws_size,
                              hipStream_t stream)
{
    const float* modulations = (const float*)d_in[0]; // [1024, 256]
    const float* x           = (const float*)d_in[1]; // [1024, 512]
    const float* weight      = (const float*)d_in[2]; // [512, 512]
    const float* bias        = (const float*)d_in[3]; // [512]
    const float* mod_w       = (const float*)d_in[4]; // [512, 256]
    const float* mod_b       = (const float*)d_in[5]; // [512]
    float* out = (float*)d_out;                       // [1024, 512]

    char* wsb = (char*)d_ws;
    float* colsum         = (float*)wsb;                                 // 2 KB
    unsigned short* w_bf  = (unsigned short*)(wsb + 4096);               // 512 KB
    unsigned short* t_bf  = (unsigned short*)(wsb + 4096 + 524288);      // 1 MB

    prep_w<<<IN_DIMS / 64, 256, 0, stream>>>(weight, colsum, w_bf);

    gemm_mod<<<dim3(IN_DIMS / 64, B_DIM / 64), 256, 0, stream>>>(
        modulations, mod_w, mod_b, x, colsum, t_bf);

    gemm_out<<<dim3(OUT_DIMS / 64, B_DIM / 64), 256, 0, stream>>>(
        t_bf, w_bf, bias, out);
}